// Round 11
// baseline (271.888 us; speedup 1.0000x reference)
//
#include <hip/hip_runtime.h>
#include <math.h>

#define B_ 8
#define N_ 1024
#define D_ 384
#define NH_ 8
#define HD_ 48
#define HID2_ 1536
#define HID_ 768
#define M_ (B_*N_)   /* 8192 */

typedef __attribute__((ext_vector_type(4))) float f32x4;
typedef __attribute__((ext_vector_type(2))) float f32x2;
typedef __attribute__((ext_vector_type(8))) short bf16x8;  // 8 bf16 raw bits
typedef __attribute__((ext_vector_type(4))) short bf16x4;  // 4 bf16 raw bits
typedef __attribute__((ext_vector_type(2))) unsigned u32x2;
typedef __attribute__((ext_vector_type(4))) unsigned u32x4;

__device__ inline unsigned short f2bf(float f) {
    unsigned u = __builtin_bit_cast(unsigned, f);
    u += 0x7fff + ((u >> 16) & 1);        // RNE
    return (unsigned short)(u >> 16);
}
__device__ inline float bf2f(unsigned short h) {
    unsigned u = ((unsigned)h) << 16;
    return __builtin_bit_cast(float, u);
}
__device__ inline unsigned cvtpk_bf16(float lo, float hi) {
    unsigned r;
    asm("v_cvt_pk_bf16_f32 %0, %1, %2" : "=v"(r) : "v"(lo), "v"(hi));
    return r;
}
__device__ inline f32x4 mfma16(bf16x4 a, bf16x4 b, f32x4 c) {
#if __has_builtin(__builtin_amdgcn_mfma_f32_16x16x16bf16_1k)
    return __builtin_amdgcn_mfma_f32_16x16x16bf16_1k(a, b, c, 0, 0, 0);
#else
    asm("v_mfma_f32_16x16x16_bf16 %0, %1, %2, %0" : "+v"(c) : "v"(a), "v"(b));
    return c;
#endif
}
// async global->LDS, 16B per lane; LDS dest is wave-uniform base + lane*16
__device__ inline void gld_lds16(const unsigned short* g, unsigned short* l) {
    __builtin_amdgcn_global_load_lds(
        (const __attribute__((address_space(1))) unsigned int*)(const void*)g,
        (__attribute__((address_space(3))) unsigned int*)(void*)l,
        16, 0, 0);
}

// ------------- fused fp32 -> bf16 convert for 4 weight tensors ------------
__global__ __launch_bounds__(256) void cvt4_kernel(
    const float* __restrict__ s1, const float* __restrict__ s2,
    const float* __restrict__ s3, const float* __restrict__ s4,
    int c1, int c2, int c3, int c4, unsigned short* __restrict__ out) {
    int i = blockIdx.x * 256 + threadIdx.x;
    if (i >= c1 + c2 + c3 + c4) return;
    const float* src; int off = i;
    if (i < c1) { src = s1; }
    else if (i < c1 + c2) { src = s2; off = i - c1; }
    else if (i < c1 + c2 + c3) { src = s3; off = i - c1 - c2; }
    else { src = s4; off = i - c1 - c2 - c3; }
    f32x4 v = *(const f32x4*)(src + (size_t)off*4);
    ushort4 o;
    o.x = f2bf(v[0]); o.y = f2bf(v[1]); o.z = f2bf(v[2]); o.w = f2bf(v[3]);
    *(ushort4*)(out + (size_t)i*4) = o;
}

// ---------------- LayerNorm: one wave per row, bf16 out ----------------
__global__ __launch_bounds__(256) void ln_kernel(
    const float* __restrict__ x, const float* __restrict__ g,
    const float* __restrict__ b, unsigned short* __restrict__ out) {
    int wave = threadIdx.x >> 6;
    int lane = threadIdx.x & 63;
    int row  = blockIdx.x * 4 + wave;
    const float* xr = x + (size_t)row * D_;
    f32x2 v[3];
    float s = 0.f;
    #pragma unroll
    for (int i = 0; i < 3; ++i) {
        v[i] = *(const f32x2*)(xr + i*128 + lane*2);
        s += v[i][0] + v[i][1];
    }
    #pragma unroll
    for (int off = 1; off < 64; off <<= 1) s += __shfl_xor(s, off);
    float mean = s * (1.0f/D_);
    float vs = 0.f;
    #pragma unroll
    for (int i = 0; i < 3; ++i) {
        float t0 = v[i][0]-mean, t1 = v[i][1]-mean;
        vs += t0*t0 + t1*t1;
    }
    #pragma unroll
    for (int off = 1; off < 64; off <<= 1) vs += __shfl_xor(vs, off);
    float rstd = rsqrtf(vs * (1.0f/D_) + 1e-5f);
    unsigned short* orow = out + (size_t)row * D_;
    #pragma unroll
    for (int i = 0; i < 3; ++i) {
        int d = i*128 + lane*2;
        ushort2 o;
        o.x = f2bf((v[i][0]-mean)*rstd*g[d]   + b[d]);
        o.y = f2bf((v[i][1]-mean)*rstd*g[d+1] + b[d+1]);
        *(ushort2*)(orow + d) = o;
    }
}

// ------- bf16 MFMA GEMM, 128x128 tile via global_load_lds (qkv, pin) -----
// Linear [128][32] LDS tiles (no pad: gload_lds needs contiguous lane order),
// double-buffered; loads for tile k+1 issued right after the barrier so they
// overlap the MFMA phase; the next barrier's vmcnt(0) drains them.
template<int MODE>
__global__ __launch_bounds__(256) void gemm_bf16(
    const unsigned short* __restrict__ A, const unsigned short* __restrict__ W,
    const float* __restrict__ bias, const float* __restrict__ res,
    void* __restrict__ outv, int M, int O, int K) {
    __shared__ unsigned short a_s[2][128*32];
    __shared__ unsigned short w_s[2][128*32];
    int tid = threadIdx.x;
    int o0 = blockIdx.x * 128;
    int m0 = blockIdx.y * 128;
    int wave = tid >> 6, lane = tid & 63;
    int wm = wave >> 1, wn = wave & 1;
    int lr = lane & 15, lc = lane >> 4;
    int r0 = tid >> 2, ch = tid & 3;      // staging: rows 0..63, 8-elem chunk
    int ldso = r0*32 + ch*8;              // linear-in-lane: w*1024B + lane*16B
    f32x4 acc[4][4];
    #pragma unroll
    for (int i=0;i<4;++i)
      #pragma unroll
      for (int j=0;j<4;++j) acc[i][j] = (f32x4){0.f,0.f,0.f,0.f};

    const unsigned short* pa0 = A + (size_t)(m0+r0)*K + ch*8;
    const unsigned short* pa1 = A + (size_t)(m0+r0+64)*K + ch*8;
    const unsigned short* pw0 = W + (size_t)(o0+r0)*K + ch*8;
    const unsigned short* pw1 = W + (size_t)(o0+r0+64)*K + ch*8;

    // prologue: issue tile 0 into buf 0
    gld_lds16(pa0, &a_s[0][ldso]);
    gld_lds16(pa1, &a_s[0][64*32 + ldso]);
    gld_lds16(pw0, &w_s[0][ldso]);
    gld_lds16(pw1, &w_s[0][64*32 + ldso]);
    pa0 += 32; pa1 += 32; pw0 += 32; pw1 += 32;

    int buf = 0;
    for (int k0 = 0; k0 < K; k0 += 32) {
        __syncthreads();            // drains outstanding gload_lds + syncs
        if (k0 + 32 < K) {
            int nb = buf ^ 1;
            gld_lds16(pa0, &a_s[nb][ldso]);
            gld_lds16(pa1, &a_s[nb][64*32 + ldso]);
            gld_lds16(pw0, &w_s[nb][ldso]);
            gld_lds16(pw1, &w_s[nb][64*32 + ldso]);
            pa0 += 32; pa1 += 32; pw0 += 32; pw1 += 32;
        }
        bf16x8 af[4], wf[4];
        #pragma unroll
        for (int i = 0; i < 4; ++i)
            af[i] = *(const bf16x8*)&a_s[buf][(wm*64 + i*16 + lr)*32 + lc*8];
        #pragma unroll
        for (int j = 0; j < 4; ++j)
            wf[j] = *(const bf16x8*)&w_s[buf][(wn*64 + j*16 + lr)*32 + lc*8];
        #pragma unroll
        for (int i = 0; i < 4; ++i)
            #pragma unroll
            for (int j = 0; j < 4; ++j)
                acc[i][j] = __builtin_amdgcn_mfma_f32_16x16x32_bf16(
                    af[i], wf[j], acc[i][j], 0, 0, 0);
        buf ^= 1;
    }
    #pragma unroll
    for (int i = 0; i < 4; ++i) {
        int mbase = m0 + wm*64 + i*16 + lc*4;
        #pragma unroll
        for (int j = 0; j < 4; ++j) {
            int oc = o0 + wn*64 + j*16 + lr;
            float bv = bias[oc];
            #pragma unroll
            for (int r = 0; r < 4; ++r) {
                int m = mbase + r;
                float v = acc[i][j][r] + bv;
                if (MODE == 1) {
                    ((float*)outv)[(size_t)m*O + oc] = v + res[(size_t)m*O + oc];
                } else {
                    ((unsigned short*)outv)[(size_t)m*O + oc] = f2bf(v);
                }
            }
        }
    }
}

// ------- bf16 MFMA GEMM, 64x64 tile (for small O: proj, pout) ------------
template<int MODE>
__global__ __launch_bounds__(256) void gemm_bf16_s(
    const unsigned short* __restrict__ A, const unsigned short* __restrict__ W,
    const float* __restrict__ bias, const float* __restrict__ res,
    void* __restrict__ outv, int M, int O, int K) {
    __shared__ unsigned short a_s[64][72];
    __shared__ unsigned short w_s[64][72];
    int tid = threadIdx.x;
    int o0 = blockIdx.x * 64;
    int m0 = blockIdx.y * 64;
    int wave = tid >> 6, lane = tid & 63;
    int lr = lane & 15, lc = lane >> 4;
    int r = tid >> 2, c = (tid & 3) * 16;
    f32x4 acc[4];
    #pragma unroll
    for (int i=0;i<4;++i) acc[i] = (f32x4){0.f,0.f,0.f,0.f};

    const unsigned short* pa = A + (size_t)(m0+r)*K + c;
    const unsigned short* pw = W + (size_t)(o0+r)*K + c;
    bf16x8 a0 = *(const bf16x8*)pa, a1 = *(const bf16x8*)(pa+8);
    bf16x8 w0 = *(const bf16x8*)pw, w1 = *(const bf16x8*)(pw+8);

    for (int k0 = 0; k0 < K; k0 += 64) {
        __syncthreads();
        *(bf16x8*)&a_s[r][c]   = a0;
        *(bf16x8*)&a_s[r][c+8] = a1;
        *(bf16x8*)&w_s[r][c]   = w0;
        *(bf16x8*)&w_s[r][c+8] = w1;
        __syncthreads();
        if (k0 + 64 < K) {
            pa += 64; pw += 64;
            a0 = *(const bf16x8*)pa; a1 = *(const bf16x8*)(pa+8);
            w0 = *(const bf16x8*)pw; w1 = *(const bf16x8*)(pw+8);
        }
        #pragma unroll
        for (int ks = 0; ks < 2; ++ks) {
            bf16x8 wf = *(const bf16x8*)&w_s[wave*16 + lr][ks*32 + lc*8];
            #pragma unroll
            for (int i = 0; i < 4; ++i) {
                bf16x8 af = *(const bf16x8*)&a_s[i*16 + lr][ks*32 + lc*8];
                acc[i] = __builtin_amdgcn_mfma_f32_16x16x32_bf16(af, wf, acc[i], 0,0,0);
            }
        }
    }
    int oc = o0 + wave*16 + lr;
    float bv = bias[oc];
    #pragma unroll
    for (int i = 0; i < 4; ++i) {
        #pragma unroll
        for (int rr = 0; rr < 4; ++rr) {
            int m = m0 + i*16 + lc*4 + rr;
            float v = acc[i][rr] + bv;
            if (MODE == 1) {
                ((float*)outv)[(size_t)m*O + oc] = v + res[(size_t)m*O + oc];
            } else {
                ((unsigned short*)outv)[(size_t)m*O + oc] = f2bf(v);
            }
        }
    }
}

// ---------------- Flash attention, fixed-reference softmax ----------------
// grid (B*NH, N/64), 256 thr = 4 waves. Scores bounded (LN inputs, 0.02
// weights, bias <= 0) -> constant reference 16 in log2 domain:
// P = exp2(s*scale2 + |i-j|*decay - 16). Shift-invariant. scale2 applied
// in fp32 here (NOT folded into bf16 weights -> R10 absmax regression probe).
__global__ __launch_bounds__(256) void attn_mfma(
    const unsigned short* __restrict__ qkv, unsigned short* __restrict__ out) {
    __shared__ unsigned short k_s[2][64][72];   // [buf][kv][d], cols 48+ zero
    __shared__ unsigned short vt_s[2][48][72];  // [buf][d][kv]
    int tid = threadIdx.x;
    int wave = tid >> 6, lane = tid & 63;
    int lr = lane & 15, lc = lane >> 4;
    int b = blockIdx.x >> 3, h = blockIdx.x & 7;
    int q0 = blockIdx.y * 64;
    const float LOG2E = 1.4426950408889634f;
    float decay_nats = logf(1.0f - exp2f(-2.0f - 0.5f*(float)h));  // < 0
    float decay = decay_nats * LOG2E;
    const float scale2 = 0.14433756729740643f * LOG2E;
    const bf16x8 zero8 = {0,0,0,0,0,0,0,0};

    // band tile range (block-uniform)
    int bandi = (int)(20.0f / (-decay_nats));
    int lo = q0 - bandi - 63;
    int kt_lo = lo > 0 ? (lo >> 6) : 0;
    int kt_hi = (q0 + 63 + bandi) >> 6;
    if (kt_hi > 15) kt_hi = 15;

    // zero the k_s pad region of both buffers once (never rewritten)
    if (tid < 192) {
        int zr = tid / 3, zc = 48 + (tid % 3) * 8;
        *(bf16x8*)&k_s[0][zr][zc] = zero8;
        *(bf16x8*)&k_s[1][zr][zc] = zero8;
    }

    int q = q0 + wave*16 + lr;
    float qqf = (float)q;
    const unsigned short* qrow = qkv + ((size_t)b*N_ + q)*1152 + h*48;
    bf16x8 qf0 = *(const bf16x8*)(qrow + lc*8);
    bf16x8 qf1 = zero8;
    if (lc < 2) qf1 = *(const bf16x8*)(qrow + 32 + lc*8);

    // K staging: chunk s -> row s/6, col (s%6)*8 ; thread covers s=tid and
    // (tid<128) s=tid+256.
    const unsigned short* kbase = qkv + (size_t)b*N_*1152 + D_ + h*48;
    int kr0 = tid / 6, kc0 = (tid % 6) * 8;
    bool kact1 = tid < 128;
    int s1 = kact1 ? tid + 256 : 0;
    int kr1 = s1 / 6, kc1 = (s1 % 6) * 8;
    const unsigned short* kp0 = kbase + (size_t)(kt_lo*64 + kr0)*1152 + kc0;
    const unsigned short* kp1 = kbase + (size_t)(kt_lo*64 + kr1)*1152 + kc1;

    // V staging: thread t<192 owns d-pair vd2=(t>>3)*2, kv-chunk vch=t&7
    int vd2 = (tid >> 3) * 2;
    int vch = tid & 7;
    bool vact = tid < 192;
    const unsigned short* vp = kbase + D_ + (size_t)(kt_lo*64 + vch*8)*1152 + vd2;

    // prologue: load first tile into regs; advance pointers to next tile
    bf16x8 rk0 = *(const bf16x8*)kp0;  kp0 += 64*1152;
    bf16x8 rk1 = zero8;
    if (kact1) rk1 = *(const bf16x8*)kp1;
    kp1 += 64*1152;
    unsigned rv[8];
    if (vact) {
        #pragma unroll
        for (int i = 0; i < 8; ++i)
            rv[i] = *(const unsigned*)(vp + (size_t)i*1152);
    }
    vp += 64*1152;

    float l_loc = 0.f;                 // lane-local partial of l
    f32x4 oacc[3];
    #pragma unroll
    for (int i=0;i<3;++i) oacc[i] = (f32x4){0.f,0.f,0.f,0.f};

    int cur = 0;
    for (int kt = kt_lo; kt <= kt_hi; ++kt) {
        int n0 = kt * 64;
        // STAGE_WRITE buf[cur] from regs
        *(bf16x8*)&k_s[cur][kr0][kc0] = rk0;
        if (kact1) *(bf16x8*)&k_s[cur][kr1][kc1] = rk1;
        if (vact) {
            u32x4 wlo, whi;
            #pragma unroll
            for (int i = 0; i < 4; ++i) {
                wlo[i] = (rv[2*i] & 0xffffu) | (rv[2*i+1] << 16);
                whi[i] = (rv[2*i] >> 16)    | (rv[2*i+1] & 0xffff0000u);
            }
            *(bf16x8*)&vt_s[cur][vd2]  [vch*8] = __builtin_bit_cast(bf16x8, wlo);
            *(bf16x8*)&vt_s[cur][vd2+1][vch*8] = __builtin_bit_cast(bf16x8, whi);
        }
        __syncthreads();
        // ISSUE next tile's loads (overlap the compute below)
        if (kt < kt_hi) {
            rk0 = *(const bf16x8*)kp0;  kp0 += 64*1152;
            if (kact1) rk1 = *(const bf16x8*)kp1;
            kp1 += 64*1152;
            if (vact) {
                #pragma unroll
                for (int i = 0; i < 8; ++i)
                    rv[i] = *(const unsigned*)(vp + (size_t)i*1152);
            }
            vp += 64*1152;
        }
        // S^T = K . Q^T : sc[f][r] = rawscore(q=lr, k=n0+f*16+lc*4+r)
        f32x4 sc[4];
        #pragma unroll
        for (int f = 0; f < 4; ++f) {
            sc[f] = (f32x4){0.f,0.f,0.f,0.f};
            bf16x8 kf0 = *(const bf16x8*)&k_s[cur][f*16 + lr][lc*8];
            bf16x8 kf1 = *(const bf16x8*)&k_s[cur][f*16 + lr][32 + lc*8];
            sc[f] = __builtin_amdgcn_mfma_f32_16x16x32_bf16(kf0, qf0, sc[f],0,0,0);
            sc[f] = __builtin_amdgcn_mfma_f32_16x16x32_bf16(kf1, qf1, sc[f],0,0,0);
        }
        // P = exp2(s*scale2 + |i-j|*decay - 16); accumulate l lane-locally
        float base = qqf - (float)(n0 + lc*4);
        float p[4][4];
        #pragma unroll
        for (int f = 0; f < 4; ++f)
            #pragma unroll
            for (int r = 0; r < 4; ++r) {
                float d = base - (float)(f*16 + r);
                float s2 = fmaf(fabsf(d), decay,
                                fmaf(sc[f][r], scale2, -16.0f));
                p[f][r] = __builtin_amdgcn_exp2f(s2);
                l_loc += p[f][r];
            }
        // P fragments (T12 pack)
        bf16x4 pfrag[4];
        #pragma unroll
        for (int f = 0; f < 4; ++f) {
            u32x2 u;
            u[0] = cvtpk_bf16(p[f][0], p[f][1]);
            u[1] = cvtpk_bf16(p[f][2], p[f][3]);
            pfrag[f] = __builtin_bit_cast(bf16x4, u);
        }
        // O^T += V^T . P^T
        #pragma unroll
        for (int f = 0; f < 4; ++f)
            #pragma unroll
            for (int md = 0; md < 3; ++md) {
                bf16x4 va = *(const bf16x4*)&vt_s[cur][md*16 + lr][f*16 + lc*4];
                oacc[md] = mfma16(va, pfrag[f], oacc[md]);
            }
        cur ^= 1;
    }
    // reduce l across the 4 lane-groups holding this q-row
    float l = l_loc;
    l += __shfl_xor(l, 16);
    l += __shfl_xor(l, 32);
    float inv_l = 1.0f / l;
    #pragma unroll
    for (int md = 0; md < 3; ++md) {
        ushort4 o;
        o.x = f2bf(oacc[md][0]*inv_l);
        o.y = f2bf(oacc[md][1]*inv_l);
        o.z = f2bf(oacc[md][2]*inv_l);
        o.w = f2bf(oacc[md][3]*inv_l);
        *(ushort4*)(out + ((size_t)b*N_ + q)*D_ + h*48 + md*16 + lc*4) = o;
    }
}

// ---------------- Depthwise 3x3 conv + GELU gate, 8 ch/thread ------------
__global__ __launch_bounds__(256) void dwconv_gate_bf16(
    const unsigned short* __restrict__ h, const float* __restrict__ dw_w,
    const float* __restrict__ dw_b, unsigned short* __restrict__ g) {
    __shared__ float wt_s[9][128];   // [tap][ch: 0..63 = h1, 64..127 = h2]
    __shared__ float bs_s[128];
    int tid = threadIdx.x;
    int cg0 = blockIdx.x * 64;
    int y   = blockIdx.y;
    int b   = blockIdx.z;
    for (int i = tid; i < 1152; i += 256) {
        int tap = i >> 7, cl = i & 127;
        int gch = (cl < 64) ? (cg0 + cl) : (HID_ + cg0 + (cl - 64));
        wt_s[tap][cl] = dw_w[(size_t)gch*9 + tap];
    }
    if (tid < 128) {
        int gch = (tid < 64) ? (cg0 + tid) : (HID_ + cg0 + (tid - 64));
        bs_s[tid] = dw_b[gch];
    }
    __syncthreads();
    int x  = tid >> 3;
    int co = (tid & 7) * 8;
    int c1 = cg0 + co;
    const unsigned short* hb = h + (size_t)b*N_*HID2_;
    float acc1[8], acc2[8];
    #pragma unroll
    for (int j=0;j<8;++j) { acc1[j] = bs_s[co+j]; acc2[j] = bs_s[64+co+j]; }
    #pragma unroll
    for (int ky=0; ky<3; ++ky) {
        int yy = y + ky - 1;
        if (yy < 0 || yy >= 32) continue;
        #pragma unroll
        for (int kx=0; kx<3; ++kx) {
            int xx = x + kx - 1;
            if (xx < 0 || xx >= 32) continue;
            const unsigned short* p = hb + (size_t)(yy*32+xx)*HID2_ + c1;
            bf16x8 d1 = *(const bf16x8*)p;
            bf16x8 d2 = *(const bf16x8*)(p + HID_);
            int t = ky*3 + kx;
            f32x4 w1a = *(const f32x4*)&wt_s[t][co];
            f32x4 w1b = *(const f32x4*)&wt_s[t][co+4];
            f32x4 w2a = *(const f32x4*)&wt_s[t][64+co];
            f32x4 w2b = *(const f32x4*)&wt_s[t][64+co+4];
            #pragma unroll
            for (int j=0;j<4;++j) {
                acc1[j]   += bf2f((unsigned short)d1[j])   * w1a[j];
                acc1[j+4] += bf2f((unsigned short)d1[j+4]) * w1b[j];
                acc2[j]   += bf2f((unsigned short)d2[j])   * w2a[j];
                acc2[j+4] += bf2f((unsigned short)d2[j+4]) * w2b[j];
            }
        }
    }
    bf16x8 o;
    #pragma unroll
    for (int j=0;j<8;++j) {
        float ge = 0.5f*acc1[j]*(1.0f + erff(acc1[j]*0.70710678118f));
        o[j] = (short)f2bf(ge * acc2[j]);
    }
    *(bf16x8*)(g + (size_t)(b*N_ + y*32 + x)*HID_ + c1) = o;
}

extern "C" void kernel_launch(void* const* d_in, const int* in_sizes, int n_in,
                              void* d_out, int out_size, void* d_ws, size_t ws_size,
                              hipStream_t stream) {
    const float* x_in   = (const float*)d_in[0];
    const float* qkv_w  = (const float*)d_in[1];
    const float* qkv_b  = (const float*)d_in[2];
    const float* proj_w = (const float*)d_in[3];
    const float* proj_b = (const float*)d_in[4];
    const float* ln1_g  = (const float*)d_in[5];
    const float* ln1_b  = (const float*)d_in[6];
    const float* ln2_g  = (const float*)d_in[7];
    const float* ln2_b  = (const float*)d_in[8];
    const float* pin_w  = (const float*)d_in[9];
    const float* pin_b  = (const float*)d_in[10];
    const float* dw_w   = (const float*)d_in[11];
    const float* dw_b   = (const float*)d_in[12];
    const float* pout_w = (const float*)d_in[13];
    const float* pout_b = (const float*)d_in[14];

    float* pX = (float*)d_out;                       // residual stream fp32
    unsigned short* wXn  = (unsigned short*)d_ws;                 // [M][384]
    unsigned short* wQKV = wXn  + (size_t)M_*D_;                  // [M][1152]
    unsigned short* wAO  = wQKV + (size_t)M_*3*D_;                // [M][384]
    unsigned short* wH   = wAO  + (size_t)M_*D_;                  // [M][1536]
    unsigned short* wG   = wH   + (size_t)M_*HID2_;               // [M][768]
    unsigned short* wWq  = wG   + (size_t)M_*HID_;                // weights bf16
    unsigned short* wWp  = wWq  + (size_t)2*3*D_*D_;
    unsigned short* wWi  = wWp  + (size_t)2*D_*D_;
    unsigned short* wWo  = wWi  + (size_t)2*HID2_*D_;

    int c1 = 2*3*D_*D_/4, c2 = 2*D_*D_/4, c3 = 2*HID2_*D_/4, c4 = 2*D_*HID_/4;
    int ctot = c1 + c2 + c3 + c4;
    cvt4_kernel<<<(ctot+255)/256, 256, 0, stream>>>(
        qkv_w, proj_w, pin_w, pout_w, c1, c2, c3, c4, wWq);

    hipMemcpyAsync(pX, x_in, sizeof(float)*(size_t)M_*D_,
                   hipMemcpyDeviceToDevice, stream);

    for (int l = 0; l < 2; ++l) {
        ln_kernel<<<M_/4, 256, 0, stream>>>(pX, ln1_g + l*D_, ln1_b + l*D_, wXn);
        gemm_bf16<0><<<dim3((3*D_)/128, M_/128), 256, 0, stream>>>(
            wXn, wWq + (size_t)l*3*D_*D_, qkv_b + (size_t)l*3*D_,
            nullptr, wQKV, M_, 3*D_, D_);
        attn_mfma<<<dim3(B_*NH_, N_/64), 256, 0, stream>>>(wQKV, wAO);
        gemm_bf16_s<1><<<dim3(D_/64, M_/64), 256, 0, stream>>>(
            wAO, wWp + (size_t)l*D_*D_, proj_b + (size_t)l*D_,
            pX, pX, M_, D_, D_);
        ln_kernel<<<M_/4, 256, 0, stream>>>(pX, ln2_g + l*D_, ln2_b + l*D_, wXn);
        gemm_bf16<0><<<dim3(HID2_/128, M_/128), 256, 0, stream>>>(
            wXn, wWi + (size_t)l*HID2_*D_, pin_b + (size_t)l*HID2_,
            nullptr, wH, M_, HID2_, D_);
        dwconv_gate_bf16<<<dim3(HID_/64, 32, B_), 256, 0, stream>>>(
            wH, dw_w + (size_t)l*HID2_*9, dw_b + (size_t)l*HID2_, wG);
        gemm_bf16_s<1><<<dim3(D_/64, M_/64), 256, 0, stream>>>(
            wG, wWo + (size_t)l*D_*HID_, pout_b + (size_t)l*D_,
            pX, pX, M_, D_, HID_);
    }
}

// Round 14
// 265.962 us; speedup vs baseline: 1.0223x; 1.0223x over previous
//
#include <hip/hip_runtime.h>
#include <math.h>

#define B_ 8
#define N_ 1024
#define D_ 384
#define NH_ 8
#define HD_ 48
#define HID2_ 1536
#define HID_ 768
#define M_ (B_*N_)   /* 8192 */

typedef __attribute__((ext_vector_type(4))) float f32x4;
typedef __attribute__((ext_vector_type(2))) float f32x2;
typedef __attribute__((ext_vector_type(8))) short bf16x8;  // 8 bf16 raw bits
typedef __attribute__((ext_vector_type(4))) short bf16x4;  // 4 bf16 raw bits
typedef __attribute__((ext_vector_type(2))) unsigned u32x2;
typedef __attribute__((ext_vector_type(4))) unsigned u32x4;

__device__ inline unsigned short f2bf(float f) {
    unsigned u = __builtin_bit_cast(unsigned, f);
    u += 0x7fff + ((u >> 16) & 1);        // RNE
    return (unsigned short)(u >> 16);
}
__device__ inline float bf2f(unsigned short h) {
    unsigned u = ((unsigned)h) << 16;
    return __builtin_bit_cast(float, u);
}
__device__ inline unsigned cvtpk_bf16(float lo, float hi) {
    unsigned r;
    asm("v_cvt_pk_bf16_f32 %0, %1, %2" : "=v"(r) : "v"(lo), "v"(hi));
    return r;
}
__device__ inline f32x4 mfma16(bf16x4 a, bf16x4 b, f32x4 c) {
#if __has_builtin(__builtin_amdgcn_mfma_f32_16x16x16bf16_1k)
    return __builtin_amdgcn_mfma_f32_16x16x16bf16_1k(a, b, c, 0, 0, 0);
#else
    asm("v_mfma_f32_16x16x16_bf16 %0, %1, %2, %0" : "+v"(c) : "v"(a), "v"(b));
    return c;
#endif
}
// async global->LDS, 16B per lane; LDS dest is wave-uniform base + lane*16
__device__ inline void gld_lds16(const unsigned short* g, unsigned short* l) {
    __builtin_amdgcn_global_load_lds(
        (const __attribute__((address_space(1))) unsigned int*)(const void*)g,
        (__attribute__((address_space(3))) unsigned int*)(void*)l,
        16, 0, 0);
}

// ------------- fused fp32 -> bf16 convert for 4 weight tensors ------------
__global__ __launch_bounds__(256) void cvt4_kernel(
    const float* __restrict__ s1, const float* __restrict__ s2,
    const float* __restrict__ s3, const float* __restrict__ s4,
    int c1, int c2, int c3, int c4, unsigned short* __restrict__ out) {
    int i = blockIdx.x * 256 + threadIdx.x;
    if (i >= c1 + c2 + c3 + c4) return;
    const float* src; int off = i;
    if (i < c1) { src = s1; }
    else if (i < c1 + c2) { src = s2; off = i - c1; }
    else if (i < c1 + c2 + c3) { src = s3; off = i - c1 - c2; }
    else { src = s4; off = i - c1 - c2 - c3; }
    f32x4 v = *(const f32x4*)(src + (size_t)off*4);
    ushort4 o;
    o.x = f2bf(v[0]); o.y = f2bf(v[1]); o.z = f2bf(v[2]); o.w = f2bf(v[3]);
    *(ushort4*)(out + (size_t)i*4) = o;
}

// ---------------- LayerNorm: one wave per row, bf16 out ----------------
__global__ __launch_bounds__(256) void ln_kernel(
    const float* __restrict__ x, const float* __restrict__ g,
    const float* __restrict__ b, unsigned short* __restrict__ out) {
    int wave = threadIdx.x >> 6;
    int lane = threadIdx.x & 63;
    int row  = blockIdx.x * 4 + wave;
    const float* xr = x + (size_t)row * D_;
    f32x2 v[3];
    float s = 0.f;
    #pragma unroll
    for (int i = 0; i < 3; ++i) {
        v[i] = *(const f32x2*)(xr + i*128 + lane*2);
        s += v[i][0] + v[i][1];
    }
    #pragma unroll
    for (int off = 1; off < 64; off <<= 1) s += __shfl_xor(s, off);
    float mean = s * (1.0f/D_);
    float vs = 0.f;
    #pragma unroll
    for (int i = 0; i < 3; ++i) {
        float t0 = v[i][0]-mean, t1 = v[i][1]-mean;
        vs += t0*t0 + t1*t1;
    }
    #pragma unroll
    for (int off = 1; off < 64; off <<= 1) vs += __shfl_xor(vs, off);
    float rstd = rsqrtf(vs * (1.0f/D_) + 1e-5f);
    unsigned short* orow = out + (size_t)row * D_;
    #pragma unroll
    for (int i = 0; i < 3; ++i) {
        int d = i*128 + lane*2;
        ushort2 o;
        o.x = f2bf((v[i][0]-mean)*rstd*g[d]   + b[d]);
        o.y = f2bf((v[i][1]-mean)*rstd*g[d+1] + b[d+1]);
        *(ushort2*)(orow + d) = o;
    }
}

// ------- bf16 MFMA GEMM, 128x128 tile via global_load_lds (qkv, pin) -----
// Linear [128][32] LDS tiles, double-buffered; loads for tile k+1 issued
// right after the barrier so they overlap the MFMA phase.
template<int MODE>
__global__ __launch_bounds__(256) void gemm_bf16(
    const unsigned short* __restrict__ A, const unsigned short* __restrict__ W,
    const float* __restrict__ bias, const float* __restrict__ res,
    void* __restrict__ outv, int M, int O, int K) {
    __shared__ __align__(16) unsigned short a_s[2][128*32];
    __shared__ __align__(16) unsigned short w_s[2][128*32];
    int tid = threadIdx.x;
    int o0 = blockIdx.x * 128;
    int m0 = blockIdx.y * 128;
    int wave = tid >> 6, lane = tid & 63;
    int wm = wave >> 1, wn = wave & 1;
    int lr = lane & 15, lc = lane >> 4;
    int r0 = tid >> 2, ch = tid & 3;      // staging: rows 0..63, 8-elem chunk
    int ldso = r0*32 + ch*8;              // linear-in-lane: w*1024B + lane*16B
    f32x4 acc[4][4];
    #pragma unroll
    for (int i=0;i<4;++i)
      #pragma unroll
      for (int j=0;j<4;++j) acc[i][j] = (f32x4){0.f,0.f,0.f,0.f};

    const unsigned short* pa0 = A + (size_t)(m0+r0)*K + ch*8;
    const unsigned short* pa1 = A + (size_t)(m0+r0+64)*K + ch*8;
    const unsigned short* pw0 = W + (size_t)(o0+r0)*K + ch*8;
    const unsigned short* pw1 = W + (size_t)(o0+r0+64)*K + ch*8;

    // prologue: issue tile 0 into buf 0
    gld_lds16(pa0, &a_s[0][ldso]);
    gld_lds16(pa1, &a_s[0][64*32 + ldso]);
    gld_lds16(pw0, &w_s[0][ldso]);
    gld_lds16(pw1, &w_s[0][64*32 + ldso]);
    pa0 += 32; pa1 += 32; pw0 += 32; pw1 += 32;

    int buf = 0;
    for (int k0 = 0; k0 < K; k0 += 32) {
        __syncthreads();            // drains outstanding gload_lds + syncs
        if (k0 + 32 < K) {
            int nb = buf ^ 1;
            gld_lds16(pa0, &a_s[nb][ldso]);
            gld_lds16(pa1, &a_s[nb][64*32 + ldso]);
            gld_lds16(pw0, &w_s[nb][ldso]);
            gld_lds16(pw1, &w_s[nb][64*32 + ldso]);
            pa0 += 32; pa1 += 32; pw0 += 32; pw1 += 32;
        }
        bf16x8 af[4], wf[4];
        #pragma unroll
        for (int i = 0; i < 4; ++i)
            af[i] = *(const bf16x8*)&a_s[buf][(wm*64 + i*16 + lr)*32 + lc*8];
        #pragma unroll
        for (int j = 0; j < 4; ++j)
            wf[j] = *(const bf16x8*)&w_s[buf][(wn*64 + j*16 + lr)*32 + lc*8];
        #pragma unroll
        for (int i = 0; i < 4; ++i)
            #pragma unroll
            for (int j = 0; j < 4; ++j)
                acc[i][j] = __builtin_amdgcn_mfma_f32_16x16x32_bf16(
                    af[i], wf[j], acc[i][j], 0, 0, 0);
        buf ^= 1;
    }
    #pragma unroll
    for (int i = 0; i < 4; ++i) {
        int mbase = m0 + wm*64 + i*16 + lc*4;
        #pragma unroll
        for (int j = 0; j < 4; ++j) {
            int oc = o0 + wn*64 + j*16 + lr;
            float bv = bias[oc];
            #pragma unroll
            for (int r = 0; r < 4; ++r) {
                int m = mbase + r;
                float v = acc[i][j][r] + bv;
                if (MODE == 1) {
                    ((float*)outv)[(size_t)m*O + oc] = v + res[(size_t)m*O + oc];
                } else {
                    ((unsigned short*)outv)[(size_t)m*O + oc] = f2bf(v);
                }
            }
        }
    }
}

// ------- bf16 MFMA GEMM, 64x64 tile, double-buffered (proj, pout) --------
// One barrier per K-step: write buf[cur] -> barrier -> load next tile regs
// (overlaps MFMA) -> MFMA from buf[cur]. Two-iteration write-reuse distance
// crosses a barrier -> race-free (same structure as attn pipeline).
template<int MODE>
__global__ __launch_bounds__(256) void gemm_bf16_s(
    const unsigned short* __restrict__ A, const unsigned short* __restrict__ W,
    const float* __restrict__ bias, const float* __restrict__ res,
    void* __restrict__ outv, int M, int O, int K) {
    __shared__ unsigned short a_s[2][64][72];
    __shared__ unsigned short w_s[2][64][72];
    int tid = threadIdx.x;
    int o0 = blockIdx.x * 64;
    int m0 = blockIdx.y * 64;
    int wave = tid >> 6, lane = tid & 63;
    int lr = lane & 15, lc = lane >> 4;
    int r = tid >> 2, c = (tid & 3) * 16;
    f32x4 acc[4];
    #pragma unroll
    for (int i=0;i<4;++i) acc[i] = (f32x4){0.f,0.f,0.f,0.f};

    const unsigned short* pa = A + (size_t)(m0+r)*K + c;
    const unsigned short* pw = W + (size_t)(o0+r)*K + c;
    bf16x8 a0 = *(const bf16x8*)pa, a1 = *(const bf16x8*)(pa+8);
    bf16x8 w0 = *(const bf16x8*)pw, w1 = *(const bf16x8*)(pw+8);

    int cur = 0;
    for (int k0 = 0; k0 < K; k0 += 64) {
        *(bf16x8*)&a_s[cur][r][c]   = a0;
        *(bf16x8*)&a_s[cur][r][c+8] = a1;
        *(bf16x8*)&w_s[cur][r][c]   = w0;
        *(bf16x8*)&w_s[cur][r][c+8] = w1;
        __syncthreads();
        if (k0 + 64 < K) {
            pa += 64; pw += 64;
            a0 = *(const bf16x8*)pa; a1 = *(const bf16x8*)(pa+8);
            w0 = *(const bf16x8*)pw; w1 = *(const bf16x8*)(pw+8);
        }
        #pragma unroll
        for (int ks = 0; ks < 2; ++ks) {
            bf16x8 wf = *(const bf16x8*)&w_s[cur][wave*16 + lr][ks*32 + lc*8];
            #pragma unroll
            for (int i = 0; i < 4; ++i) {
                bf16x8 af = *(const bf16x8*)&a_s[cur][i*16 + lr][ks*32 + lc*8];
                acc[i] = __builtin_amdgcn_mfma_f32_16x16x32_bf16(af, wf, acc[i], 0,0,0);
            }
        }
        cur ^= 1;
    }
    int oc = o0 + wave*16 + lr;
    float bv = bias[oc];
    #pragma unroll
    for (int i = 0; i < 4; ++i) {
        #pragma unroll
        for (int rr = 0; rr < 4; ++rr) {
            int m = m0 + i*16 + lc*4 + rr;
            float v = acc[i][rr] + bv;
            if (MODE == 1) {
                ((float*)outv)[(size_t)m*O + oc] = v + res[(size_t)m*O + oc];
            } else {
                ((unsigned short*)outv)[(size_t)m*O + oc] = f2bf(v);
            }
        }
    }
}

// ---------------- Flash attention, fixed-reference softmax ----------------
// (R11-proven version, [M][1152] qkv layout.) Scores bounded -> constant
// reference 16 in log2 domain: P = exp2(s*scale2 + |i-j|*decay - 16).
// Double-buffered LDS, next-tile loads issued right after the barrier.
__global__ __launch_bounds__(256) void attn_mfma(
    const unsigned short* __restrict__ qkv, unsigned short* __restrict__ out) {
    __shared__ unsigned short k_s[2][64][72];   // [buf][kv][d], cols 48+ zero
    __shared__ unsigned short vt_s[2][48][72];  // [buf][d][kv]
    int tid = threadIdx.x;
    int wave = tid >> 6, lane = tid & 63;
    int lr = lane & 15, lc = lane >> 4;
    int b = blockIdx.x >> 3, h = blockIdx.x & 7;
    int q0 = blockIdx.y * 64;
    const float LOG2E = 1.4426950408889634f;
    float decay_nats = logf(1.0f - exp2f(-2.0f - 0.5f*(float)h));  // < 0
    float decay = decay_nats * LOG2E;
    const float scale2 = 0.14433756729740643f * LOG2E;
    const bf16x8 zero8 = {0,0,0,0,0,0,0,0};

    // band tile range (block-uniform)
    int bandi = (int)(20.0f / (-decay_nats));
    int lo = q0 - bandi - 63;
    int kt_lo = lo > 0 ? (lo >> 6) : 0;
    int kt_hi = (q0 + 63 + bandi) >> 6;
    if (kt_hi > 15) kt_hi = 15;

    // zero the k_s pad region of both buffers once (never rewritten)
    if (tid < 192) {
        int zr = tid / 3, zc = 48 + (tid % 3) * 8;
        *(bf16x8*)&k_s[0][zr][zc] = zero8;
        *(bf16x8*)&k_s[1][zr][zc] = zero8;
    }

    int q = q0 + wave*16 + lr;
    float qqf = (float)q;
    const unsigned short* qrow = qkv + ((size_t)b*N_ + q)*1152 + h*48;
    bf16x8 qf0 = *(const bf16x8*)(qrow + lc*8);
    bf16x8 qf1 = zero8;
    if (lc < 2) qf1 = *(const bf16x8*)(qrow + 32 + lc*8);

    // K staging: chunk s -> row s/6, col (s%6)*8 ; thread covers s=tid and
    // (tid<128) s=tid+256.
    const unsigned short* kbase = qkv + (size_t)b*N_*1152 + D_ + h*48;
    int kr0 = tid / 6, kc0 = (tid % 6) * 8;
    bool kact1 = tid < 128;
    int s1 = kact1 ? tid + 256 : 0;
    int kr1 = s1 / 6, kc1 = (s1 % 6) * 8;
    const unsigned short* kp0 = kbase + (size_t)(kt_lo*64 + kr0)*1152 + kc0;
    const unsigned short* kp1 = kbase + (size_t)(kt_lo*64 + kr1)*1152 + kc1;

    // V staging: thread t<192 owns d-pair vd2=(t>>3)*2, kv-chunk vch=t&7
    int vd2 = (tid >> 3) * 2;
    int vch = tid & 7;
    bool vact = tid < 192;
    const unsigned short* vp = kbase + D_ + (size_t)(kt_lo*64 + vch*8)*1152 + vd2;

    // prologue: load first tile into regs; advance pointers to next tile
    bf16x8 rk0 = *(const bf16x8*)kp0;  kp0 += 64*1152;
    bf16x8 rk1 = zero8;
    if (kact1) rk1 = *(const bf16x8*)kp1;
    kp1 += 64*1152;
    unsigned rv[8];
    if (vact) {
        #pragma unroll
        for (int i = 0; i < 8; ++i)
            rv[i] = *(const unsigned*)(vp + (size_t)i*1152);
    }
    vp += 64*1152;

    float l_loc = 0.f;                 // lane-local partial of l
    f32x4 oacc[3];
    #pragma unroll
    for (int i=0;i<3;++i) oacc[i] = (f32x4){0.f,0.f,0.f,0.f};

    int cur = 0;
    for (int kt = kt_lo; kt <= kt_hi; ++kt) {
        int n0 = kt * 64;
        // STAGE_WRITE buf[cur] from regs
        *(bf16x8*)&k_s[cur][kr0][kc0] = rk0;
        if (kact1) *(bf16x8*)&k_s[cur][kr1][kc1] = rk1;
        if (vact) {
            u32x4 wlo, whi;
            #pragma unroll
            for (int i = 0; i < 4; ++i) {
                wlo[i] = (rv[2*i] & 0xffffu) | (rv[2*i+1] << 16);
                whi[i] = (rv[2*i] >> 16)    | (rv[2*i+1] & 0xffff0000u);
            }
            *(bf16x8*)&vt_s[cur][vd2]  [vch*8] = __builtin_bit_cast(bf16x8, wlo);
            *(bf16x8*)&vt_s[cur][vd2+1][vch*8] = __builtin_bit_cast(bf16x8, whi);
        }
        __syncthreads();
        // ISSUE next tile's loads (overlap the compute below)
        if (kt < kt_hi) {
            rk0 = *(const bf16x8*)kp0;  kp0 += 64*1152;
            if (kact1) rk1 = *(const bf16x8*)kp1;
            kp1 += 64*1152;
            if (vact) {
                #pragma unroll
                for (int i = 0; i < 8; ++i)
                    rv[i] = *(const unsigned*)(vp + (size_t)i*1152);
            }
            vp += 64*1152;
        }
        // S^T = K . Q^T : sc[f][r] = rawscore(q=lr, k=n0+f*16+lc*4+r)
        f32x4 sc[4];
        #pragma unroll
        for (int f = 0; f < 4; ++f) {
            sc[f] = (f32x4){0.f,0.f,0.f,0.f};
            bf16x8 kf0 = *(const bf16x8*)&k_s[cur][f*16 + lr][lc*8];
            bf16x8 kf1 = *(const bf16x8*)&k_s[cur][f*16 + lr][32 + lc*8];
            sc[f] = __builtin_amdgcn_mfma_f32_16x16x32_bf16(kf0, qf0, sc[f],0,0,0);
            sc[f] = __builtin_amdgcn_mfma_f32_16x16x32_bf16(kf1, qf1, sc[f],0,0,0);
        }
        // P = exp2(s*scale2 + |i-j|*decay - 16); accumulate l lane-locally
        float base = qqf - (float)(n0 + lc*4);
        float p[4][4];
        #pragma unroll
        for (int f = 0; f < 4; ++f)
            #pragma unroll
            for (int r = 0; r < 4; ++r) {
                float d = base - (float)(f*16 + r);
                float s2 = fmaf(fabsf(d), decay,
                                fmaf(sc[f][r], scale2, -16.0f));
                p[f][r] = __builtin_amdgcn_exp2f(s2);
                l_loc += p[f][r];
            }
        // P fragments (T12 pack)
        bf16x4 pfrag[4];
        #pragma unroll
        for (int f = 0; f < 4; ++f) {
            u32x2 u;
            u[0] = cvtpk_bf16(p[f][0], p[f][1]);
            u[1] = cvtpk_bf16(p[f][2], p[f][3]);
            pfrag[f] = __builtin_bit_cast(bf16x4, u);
        }
        // O^T += V^T . P^T
        #pragma unroll
        for (int f = 0; f < 4; ++f)
            #pragma unroll
            for (int md = 0; md < 3; ++md) {
                bf16x4 va = *(const bf16x4*)&vt_s[cur][md*16 + lr][f*16 + lc*4];
                oacc[md] = mfma16(va, pfrag[f], oacc[md]);
            }
        cur ^= 1;
    }
    // reduce l across the 4 lane-groups holding this q-row
    float l = l_loc;
    l += __shfl_xor(l, 16);
    l += __shfl_xor(l, 32);
    float inv_l = 1.0f / l;
    #pragma unroll
    for (int md = 0; md < 3; ++md) {
        ushort4 o;
        o.x = f2bf(oacc[md][0]*inv_l);
        o.y = f2bf(oacc[md][1]*inv_l);
        o.z = f2bf(oacc[md][2]*inv_l);
        o.w = f2bf(oacc[md][3]*inv_l);
        *(ushort4*)(out + ((size_t)b*N_ + q)*D_ + h*48 + md*16 + lc*4) = o;
    }
}

// ---------------- Depthwise 3x3 conv + GELU gate, 8 ch/thread ------------
__global__ __launch_bounds__(256) void dwconv_gate_bf16(
    const unsigned short* __restrict__ h, const float* __restrict__ dw_w,
    const float* __restrict__ dw_b, unsigned short* __restrict__ g) {
    __shared__ float wt_s[9][128];   // [tap][ch: 0..63 = h1, 64..127 = h2]
    __shared__ float bs_s[128];
    int tid = threadIdx.x;
    int cg0 = blockIdx.x * 64;
    int y   = blockIdx.y;
    int b   = blockIdx.z;
    for (int i = tid; i < 1152; i += 256) {
        int tap = i >> 7, cl = i & 127;
        int gch = (cl < 64) ? (cg0 + cl) : (HID_ + cg0 + (cl - 64));
        wt_s[tap][cl] = dw_w[(size_t)gch*9 + tap];
    }
    if (tid < 128) {
        int gch = (tid < 64) ? (cg0 + tid) : (HID_ + cg0 + (tid - 64));
        bs_s[tid] = dw_b[gch];
    }
    __syncthreads();
    int x  = tid >> 3;
    int co = (tid & 7) * 8;
    int c1 = cg0 + co;
    const unsigned short* hb = h + (size_t)b*N_*HID2_;
    float acc1[8], acc2[8];
    #pragma unroll
    for (int j=0;j<8;++j) { acc1[j] = bs_s[co+j]; acc2[j] = bs_s[64+co+j]; }
    #pragma unroll
    for (int ky=0; ky<3; ++ky) {
        int yy = y + ky - 1;
        if (yy < 0 || yy >= 32) continue;
        #pragma unroll
        for (int kx=0; kx<3; ++kx) {
            int xx = x + kx - 1;
            if (xx < 0 || xx >= 32) continue;
            const unsigned short* p = hb + (size_t)(yy*32+xx)*HID2_ + c1;
            bf16x8 d1 = *(const bf16x8*)p;
            bf16x8 d2 = *(const bf16x8*)(p + HID_);
            int t = ky*3 + kx;
            f32x4 w1a = *(const f32x4*)&wt_s[t][co];
            f32x4 w1b = *(const f32x4*)&wt_s[t][co+4];
            f32x4 w2a = *(const f32x4*)&wt_s[t][64+co];
            f32x4 w2b = *(const f32x4*)&wt_s[t][64+co+4];
            #pragma unroll
            for (int j=0;j<4;++j) {
                acc1[j]   += bf2f((unsigned short)d1[j])   * w1a[j];
                acc1[j+4] += bf2f((unsigned short)d1[j+4]) * w1b[j];
                acc2[j]   += bf2f((unsigned short)d2[j])   * w2a[j];
                acc2[j+4] += bf2f((unsigned short)d2[j+4]) * w2b[j];
            }
        }
    }
    bf16x8 o;
    #pragma unroll
    for (int j=0;j<8;++j) {
        float ge = 0.5f*acc1[j]*(1.0f + erff(acc1[j]*0.70710678118f));
        o[j] = (short)f2bf(ge * acc2[j]);
    }
    *(bf16x8*)(g + (size_t)(b*N_ + y*32 + x)*HID_ + c1) = o;
}

extern "C" void kernel_launch(void* const* d_in, const int* in_sizes, int n_in,
                              void* d_out, int out_size, void* d_ws, size_t ws_size,
                              hipStream_t stream) {
    const float* x_in   = (const float*)d_in[0];
    const float* qkv_w  = (const float*)d_in[1];
    const float* qkv_b  = (const float*)d_in[2];
    const float* proj_w = (const float*)d_in[3];
    const float* proj_b = (const float*)d_in[4];
    const float* ln1_g  = (const float*)d_in[5];
    const float* ln1_b  = (const float*)d_in[6];
    const float* ln2_g  = (const float*)d_in[7];
    const float* ln2_b  = (const float*)d_in[8];
    const float* pin_w  = (const float*)d_in[9];
    const float* pin_b  = (const float*)d_in[10];
    const float* dw_w   = (const float*)d_in[11];
    const float* dw_b   = (const float*)d_in[12];
    const float* pout_w = (const float*)d_in[13];
    const float* pout_b = (const float*)d_in[14];

    float* pX = (float*)d_out;                       // residual stream fp32
    unsigned short* wXn  = (unsigned short*)d_ws;                 // [M][384]
    unsigned short* wQKV = wXn  + (size_t)M_*D_;                  // [M][1152]
    unsigned short* wAO  = wQKV + (size_t)M_*3*D_;                // [M][384]
    unsigned short* wH   = wAO  + (size_t)M_*D_;                  // [M][1536]
    unsigned short* wG   = wH   + (size_t)M_*HID2_;               // [M][768]
    unsigned short* wWq  = wG   + (size_t)M_*HID_;                // weights bf16
    unsigned short* wWp  = wWq  + (size_t)2*3*D_*D_;
    unsigned short* wWi  = wWp  + (size_t)2*D_*D_;
    unsigned short* wWo  = wWi  + (size_t)2*HID2_*D_;

    int c1 = 2*3*D_*D_/4, c2 = 2*D_*D_/4, c3 = 2*HID2_*D_/4, c4 = 2*D_*HID_/4;
    int ctot = c1 + c2 + c3 + c4;
    cvt4_kernel<<<(ctot+255)/256, 256, 0, stream>>>(
        qkv_w, proj_w, pin_w, pout_w, c1, c2, c3, c4, wWq);

    for (int l = 0; l < 2; ++l) {
        // layer 0 sources the residual stream directly from the input;
        // pX is first written by the proj GEMM of layer 0.
        const float* resid = (l == 0) ? x_in : pX;
        ln_kernel<<<M_/4, 256, 0, stream>>>(resid, ln1_g + l*D_, ln1_b + l*D_, wXn);
        gemm_bf16<0><<<dim3((3*D_)/128, M_/128), 256, 0, stream>>>(
            wXn, wWq + (size_t)l*3*D_*D_, qkv_b + (size_t)l*3*D_,
            nullptr, wQKV, M_, 3*D_, D_);
        attn_mfma<<<dim3(B_*NH_, N_/64), 256, 0, stream>>>(wQKV, wAO);
        gemm_bf16_s<1><<<dim3(D_/64, M_/64), 256, 0, stream>>>(
            wAO, wWp + (size_t)l*D_*D_, proj_b + (size_t)l*D_,
            resid, pX, M_, D_, D_);
        ln_kernel<<<M_/4, 256, 0, stream>>>(pX, ln2_g + l*D_, ln2_b + l*D_, wXn);
        gemm_bf16<0><<<dim3(HID2_/128, M_/128), 256, 0, stream>>>(
            wXn, wWi + (size_t)l*HID2_*D_, pin_b + (size_t)l*HID2_,
            nullptr, wH, M_, HID2_, D_);
        dwconv_gate_bf16<<<dim3(HID_/64, 32, B_), 256, 0, stream>>>(
            wH, dw_w + (size_t)l*HID2_*9, dw_b + (size_t)l*HID2_, wG);
        gemm_bf16_s<1><<<dim3(D_/64, M_/64), 256, 0, stream>>>(
            wG, wWo + (size_t)l*D_*HID_, pout_b + (size_t)l*D_,
            pX, pX, M_, D_, HID_);
    }
}